// Round 2
// baseline (128.582 us; speedup 1.0000x reference)
//
#include <hip/hip_runtime.h>

#define HW      4096      // 64*64
#define W_DIM   64
#define C_IN    256
#define NK      25        // 5x5 taps
#define NQ      112       // kq padded 100 -> 112

typedef __bf16 bf16x4 __attribute__((ext_vector_type(4)));
typedef __bf16 bf16x8 __attribute__((ext_vector_type(8)));
typedef float  f32x4  __attribute__((ext_vector_type(4)));
typedef float  f32x2  __attribute__((ext_vector_type(2)));

static __device__ __forceinline__ unsigned short f2bf(float f) {
    unsigned x = __float_as_uint(f);
    return (unsigned short)((x + 0x7fffu + ((x >> 16) & 1u)) >> 16);   // RNE
}
static __device__ __forceinline__ float bflo2f(unsigned u) { return __uint_as_float(u << 16); }
static __device__ __forceinline__ float bfhi2f(unsigned u) { return __uint_as_float(u & 0xffff0000u); }

// ---------------------------------------------------------------------------
// Kernel 0: weight prep.
//  wtb[tap][kq=112 zero-pad][c=64] bf16   (encoder B panels)
//  wct[cc=64][c=256] bf16                 (compress B)
__global__ __launch_bounds__(256) void k_prep(const float* __restrict__ wenc,
                                              const float* __restrict__ wcomp,
                                              unsigned short* __restrict__ wtb,
                                              unsigned short* __restrict__ wct) {
    int idx = blockIdx.x * 256 + threadIdx.x;   // 64512 + 16384 = 80896
    if (idx < 64512) {
        int c = idx & 63;
        int t2 = idx >> 6;
        int kq = t2 % NQ;
        int tap = t2 / NQ;
        float v = (kq < 100) ? wenc[(kq * 64 + c) * 9 + tap] : 0.0f;
        wtb[idx] = f2bf(v);
    } else if (idx < 80896) {
        int j = idx - 64512;
        wct[j] = f2bf(wcomp[j]);
    }
}

// ---------------------------------------------------------------------------
// Kernel 1: MFMA 1x1 compress. GEMM M=64 px (contig p), N=64 cc, K=256 c.
// v2: 1024 threads (16 waves/CU = 50% occupancy, was 4 waves = 12.5%).
// The 16 wave-tiles (4 mt x 4 nt) map 1:1 onto 16 waves; LDS layout and
// fragment code identical to the verified 256-thread version.
__global__ __launch_bounds__(1024) void k_compress(const float* __restrict__ x,
        const unsigned short* __restrict__ wct, const float* __restrict__ bcomp,
        unsigned short* __restrict__ comp) {
    __shared__ unsigned short As[64 * 260];     // 33,280 B
    __shared__ unsigned short Bs[64 * 260];     // 33,280 B
    __shared__ float sbc[64];
    int n = blockIdx.y, p0 = blockIdx.x * 64;
    int tid = threadIdx.x, wv = tid >> 6, lane = tid & 63;
    int l15 = lane & 15, l4 = lane >> 4;
    if (tid < 64) sbc[tid] = bcomp[tid];

    const float* xp = x + (size_t)n * C_IN * HW + p0;
#pragma unroll
    for (int s = 0; s < 8; ++s) {               // A: 128 c-pairs x 64 px
        int cp = s * 16 + wv;                   // wave-uniform c-pair
        float a = xp[(size_t)(2 * cp) * HW + lane];
        float b = xp[(size_t)(2 * cp + 1) * HW + lane];
        unsigned pk = (unsigned)f2bf(a) | ((unsigned)f2bf(b) << 16);
        *(unsigned*)(As + lane * 260 + cp * 2) = pk;
    }
    const unsigned* wsrc = (const unsigned*)wct;
#pragma unroll
    for (int s = 0; s < 8; ++s) {               // B: 64 cc x 128 u32
        int slot = s * 1024 + tid;
        int cc = slot >> 7, c2 = slot & 127;
        *(unsigned*)(Bs + cc * 260 + c2 * 2) = wsrc[cc * 128 + c2];
    }
    __syncthreads();

    int mt = wv >> 2, nt = wv & 3;              // wave-tile: 16 px x 16 cc
    f32x4 acc = (f32x4){0.f, 0.f, 0.f, 0.f};
#pragma unroll
    for (int ck = 0; ck < 8; ++ck) {
        int ko = ck * 32 + l4 * 8;              // u16 offset in row
        bf16x4 alo = *(const bf16x4*)(As + (mt * 16 + l15) * 260 + ko);
        bf16x4 ahi = *(const bf16x4*)(As + (mt * 16 + l15) * 260 + ko + 4);
        bf16x8 af = __builtin_shufflevector(alo, ahi, 0, 1, 2, 3, 4, 5, 6, 7);
        bf16x4 blo = *(const bf16x4*)(Bs + (nt * 16 + l15) * 260 + ko);
        bf16x4 bhi = *(const bf16x4*)(Bs + (nt * 16 + l15) * 260 + ko + 4);
        bf16x8 bfr = __builtin_shufflevector(blo, bhi, 0, 1, 2, 3, 4, 5, 6, 7);
        acc = __builtin_amdgcn_mfma_f32_16x16x32_bf16(af, bfr, acc, 0, 0, 0);
    }
    unsigned short* op = comp + ((size_t)n * HW + p0 + mt * 16 + l4 * 4) * 64 + nt * 16;
#pragma unroll
    for (int reg = 0; reg < 4; ++reg) {
        int cc = nt * 16 + l15;
        op[(size_t)reg * 64 + l15] = f2bf(acc[reg] + sbc[cc]);
    }
}

// ---------------------------------------------------------------------------
// Kernel 2: MFMA 3x3 encoder (64->100) + fused softmax.
// v2: 4x8 px tiles, grid (128,4) = 512 blocks -> 2 blocks/CU (8 waves/CU),
// independent barrier domains let one block's staging overlap the other's
// MFMA. Halo 6x10 = 60 px; wave w -> (mt = w&1, nt in {w>>1, +2, +4, +6}).
// Epilogue is cross-wave now -> 2 extra barriers (cheap).
#define CREC    136
#define SB0E    8160                 // 60 px * 136
#define BSTRIDE 15232                // 112 * 136
#define EPI_PAD 116
__global__ __launch_bounds__(256) void k_enc(
        const unsigned short* __restrict__ comp,
        const unsigned short* __restrict__ wtb,
        const float* __restrict__ benc,
        unsigned short* __restrict__ mask) {
    __shared__ __align__(16) unsigned char smem[SB0E + 2 * BSTRIDE];  // 38,624 B
    __shared__ float sbias[NQ];
    int n = blockIdx.y, tile = blockIdx.x;      // 128 tiles: 16 rows x 8 cols
    int h0 = (tile >> 3) * 4, w0 = (tile & 7) * 8;
    int tid = threadIdx.x, wv = tid >> 6, lane = tid & 63;
    int l15 = lane & 15, l4 = lane >> 4;
    if (tid < NQ) sbias[tid] = (tid < 100) ? benc[tid] : 0.0f;

    // stage comp halo: 60 px x 128 B, zero OOB (conv zero-pad)
    const uint4* csrc = (const uint4*)(comp + (size_t)n * HW * 64);
#pragma unroll
    for (int pass = 0; pass < 2; ++pass) {
        int s = pass * 256 + tid;               // 480 slots
        if (s < 480) {
            int px = s >> 3, j = s & 7;
            int gh = h0 + px / 10 - 1, gw = w0 + px % 10 - 1;
            uint4 v = make_uint4(0u, 0u, 0u, 0u);
            if ((unsigned)gh < 64u && (unsigned)gw < 64u)
                v = csrc[(size_t)(gh * 64 + gw) * 8 + j];
            *(uint2*)(smem + px * CREC + j * 16)     = make_uint2(v.x, v.y);
            *(uint2*)(smem + px * CREC + j * 16 + 8) = make_uint2(v.z, v.w);
        }
    }
    // stage B(0) -> buf0; preload B(1) -> regs
    {
        const uint4* bs = (const uint4*)wtb;
#pragma unroll
        for (int pass = 0; pass < 4; ++pass) {
            int s = pass * 256 + tid;           // 896 slots
            if (s < 896) {
                uint4 v = bs[s];
                int kq = s >> 3, j = s & 7;
                *(uint2*)(smem + SB0E + kq * CREC + j * 16)     = make_uint2(v.x, v.y);
                *(uint2*)(smem + SB0E + kq * CREC + j * 16 + 8) = make_uint2(v.z, v.w);
            }
        }
    }
    uint4 pre[4];
    {
        const uint4* bs = (const uint4*)(wtb + (size_t)1 * NQ * 64);
#pragma unroll
        for (int pass = 0; pass < 4; ++pass) {
            int s = pass * 256 + tid;
            if (s < 896) pre[pass] = bs[s];
        }
    }

    f32x4 acc[4];
#pragma unroll
    for (int k = 0; k < 4; ++k) acc[k] = (f32x4){0.f, 0.f, 0.f, 0.f};
    int mt = wv & 1, ng = wv >> 1;
    int r_t = 2 * mt + (l15 >> 3), cl = l15 & 7;

    for (int tap = 0; tap < 9; ++tap) {
        __syncthreads();                        // separates buf reads(t-1) from writes(t+1)
        if (tap < 8) {
            unsigned char* nbuf = smem + SB0E + ((tap + 1) & 1) * BSTRIDE;
#pragma unroll
            for (int pass = 0; pass < 4; ++pass) {
                int s = pass * 256 + tid;
                if (s < 896) {
                    int kq = s >> 3, j = s & 7;
                    *(uint2*)(nbuf + kq * CREC + j * 16)     = make_uint2(pre[pass].x, pre[pass].y);
                    *(uint2*)(nbuf + kq * CREC + j * 16 + 8) = make_uint2(pre[pass].z, pre[pass].w);
                }
            }
            if (tap < 7) {
                const uint4* bs = (const uint4*)(wtb + (size_t)(tap + 2) * NQ * 64);
#pragma unroll
                for (int pass = 0; pass < 4; ++pass) {
                    int s = pass * 256 + tid;
                    if (s < 896) pre[pass] = bs[s];
                }
            }
        }
        int ti = tap / 3, tj = tap % 3;
        int apx = (r_t + ti) * 10 + cl + tj;
        const unsigned char* cbuf = smem + SB0E + (tap & 1) * BSTRIDE;
#pragma unroll
        for (int ck = 0; ck < 2; ++ck) {
            int ko = ck * 64 + l4 * 16;         // byte offset in record
            bf16x4 alo = *(const bf16x4*)(smem + apx * CREC + ko);
            bf16x4 ahi = *(const bf16x4*)(smem + apx * CREC + ko + 8);
            bf16x8 af = __builtin_shufflevector(alo, ahi, 0, 1, 2, 3, 4, 5, 6, 7);
#pragma unroll
            for (int k = 0; k < 4; ++k) {
                int nt = ng + 2 * k;
                if (nt < 7) {
                    bf16x4 blo = *(const bf16x4*)(cbuf + (nt * 16 + l15) * CREC + ko);
                    bf16x4 bhi = *(const bf16x4*)(cbuf + (nt * 16 + l15) * CREC + ko + 8);
                    bf16x8 bfr = __builtin_shufflevector(blo, bhi, 0, 1, 2, 3, 4, 5, 6, 7);
                    acc[k] = __builtin_amdgcn_mfma_f32_16x16x32_bf16(af, bfr, acc[k], 0, 0, 0);
                }
            }
        }
    }
    __syncthreads();                            // B buffers dead; epilogue overlays

    float* smE = (float*)(smem + SB0E);         // 32 x EPI_PAD f32 = 14,848 B
    unsigned short* maskn = mask + (size_t)n * HW * 100;
#pragma unroll
    for (int k = 0; k < 4; ++k) {
        int nt = ng + 2 * k;
        if (nt < 7) {
            f32x4 v = acc[k];
#pragma unroll
            for (int reg = 0; reg < 4; ++reg)
                smE[(mt * 16 + l4 * 4 + reg) * EPI_PAD + nt * 16 + l15] = v[reg];
        }
    }
    __syncthreads();                            // spill is cross-wave now
    if (tid < 128) {
        int spx = tid >> 2, q = tid & 3;        // 32 px x 4 threads
        float* row = smE + spx * EPI_PAD;
        float v[NK], mx = -1e30f;
#pragma unroll
        for (int k = 0; k < NK; ++k) {
            v[k] = row[4 * k + q] + sbias[4 * k + q];
            mx = fmaxf(mx, v[k]);
        }
        float ssum = 0.f;
#pragma unroll
        for (int k = 0; k < NK; ++k) { v[k] = __expf(v[k] - mx); ssum += v[k]; }
        float inv = 1.0f / ssum;
#pragma unroll
        for (int k = 0; k < NK; ++k) row[4 * k + q] = v[k] * inv;
    }
    __syncthreads();
#pragma unroll
    for (int i = 0; i < 4; ++i) {
        int idx = i * 256 + tid;                // 800 slots: 32 px x 25 quads
        if (idx < 800) {
            int spx = idx / 25, f4 = idx % 25;
            int rr = spx >> 3, cc2 = spx & 7;
            size_t p = (size_t)(h0 + rr) * 64 + (w0 + cc2);
            const float* sp = smE + spx * EPI_PAD + f4 * 4;
            unsigned u0 = (unsigned)f2bf(sp[0]) | ((unsigned)f2bf(sp[1]) << 16);
            unsigned u1 = (unsigned)f2bf(sp[2]) | ((unsigned)f2bf(sp[3]) << 16);
            *(uint2*)(maskn + p * 100 + f4 * 4) = make_uint2(u0, u1);
        }
    }
}

// ---------------------------------------------------------------------------
// Kernel 4: reassembly v4. 8x8 px tile x 16 c, flat grid 4096 blocks.
// LDS 25.3 KB -> 6 blocks/CU (24 waves, 75% occupancy).
// XCD-aware swizzle: each XCD owns a contiguous tile run of one (n, cg-range)
// -> x halo + mask become per-XCD-L2-resident.
// xs stride 20 dw; ms stride 108 u16 (b64 conflict-free minimum). Mask bf16.
#define XSTR2 20
#define MSTR2 108
__global__ __launch_bounds__(256, 6) void k_reassemble(const float* __restrict__ x,
        const unsigned short* __restrict__ mask, float* __restrict__ out) {
    __shared__ __align__(16) float xs[144 * XSTR2];         // 11,520 B
    __shared__ __align__(16) unsigned short ms[64 * MSTR2]; // 13,824 B
    int flat = blockIdx.x;
    int nf = (flat & 7) * 512 + (flat >> 3);    // XCD-contiguous work ids
    int tile = nf & 63, cg = (nf >> 6) & 15, n = nf >> 10;
    int h0 = (tile >> 3) * 8, w0 = (tile & 7) * 8;
    int tid = threadIdx.x;

    // stage x halo: 12x12 px x 16 c, float2 (gw base even -> pairs never
    // straddle the zero-pad boundary), zero OOB
    const float* xb = x + ((size_t)n * C_IN + cg * 16) * HW;
#pragma unroll
    for (int i = 0; i < 5; ++i) {
        int s = i * 256 + tid;                  // 16c * 12r * 6 pairs = 1152
        if (s < 1152) {
            int c = s / 72, rem = s % 72;
            int r = rem / 6, j = rem % 6;
            int gh = h0 - 2 + r, gw = w0 - 2 + j * 2;
            float2 v = make_float2(0.f, 0.f);
            if ((unsigned)gh < 64u && (unsigned)gw < 64u)
                v = *(const float2*)(xb + (size_t)c * HW + gh * W_DIM + gw);
            int px = r * 12 + j * 2;
            xs[px * XSTR2 + c]       = v.x;
            xs[(px + 1) * XSTR2 + c] = v.y;
        }
    }
    // stage mask: 64 px x 100 bf16, pure uint2 copy (conversion in k_enc)
    const unsigned short* mp = mask + (size_t)n * HW * 100;
#pragma unroll
    for (int i = 0; i < 7; ++i) {
        int s = i * 256 + tid;                  // 64 px * 25 quads = 1600
        if (s < 1600) {
            int px = s / 25, q = s % 25;
            int gp = (h0 + (px >> 3)) * W_DIM + w0 + (px & 7);
            *(uint2*)(ms + px * MSTR2 + q * 4) =
                *(const uint2*)(mp + (size_t)gp * 100 + q * 4);
        }
    }
    __syncthreads();

    int px = tid & 63, w = tid >> 6;            // lane = out px, wave = 4-ch slice
    int wx = px & 7, hy = px >> 3;
    f32x4 acc0 = {0.f, 0.f, 0.f, 0.f}, acc1 = {0.f, 0.f, 0.f, 0.f};
    f32x4 acc2 = {0.f, 0.f, 0.f, 0.f}, acc3 = {0.f, 0.f, 0.f, 0.f};
    const unsigned short* mrow = ms + px * MSTR2;
#pragma unroll
    for (int di = 0; di < 5; ++di)
#pragma unroll
        for (int dj = 0; dj < 5; ++dj) {
            int t = di * 5 + dj;
            uint2 mw = *(const uint2*)(mrow + t * 4);
            f32x4 xv = *(const f32x4*)(xs + ((hy + di) * 12 + wx + dj) * XSTR2 + w * 4);
            acc0 += xv * bflo2f(mw.x);
            acc1 += xv * bfhi2f(mw.x);
            acc2 += xv * bflo2f(mw.y);
            acc3 += xv * bfhi2f(mw.y);
        }
#pragma unroll
    for (int u = 0; u < 4; ++u) {
        float* ob = out + (((size_t)n * C_IN + cg * 16 + w * 4 + u) * 128 + 2 * (h0 + hy)) * 128
                        + 2 * (w0 + wx);
        *(float2*)(ob)       = make_float2(acc0[u], acc1[u]);
        *(float2*)(ob + 128) = make_float2(acc2[u], acc3[u]);
    }
}

// ---------------------------------------------------------------------------
extern "C" void kernel_launch(void* const* d_in, const int* in_sizes, int n_in,
                              void* d_out, int out_size, void* d_ws, size_t ws_size,
                              hipStream_t stream) {
    const float* x      = (const float*)d_in[0];
    const float* w_comp = (const float*)d_in[1];
    const float* b_comp = (const float*)d_in[2];
    const float* w_enc  = (const float*)d_in[3];
    const float* b_enc  = (const float*)d_in[4];
    float* out = (float*)d_out;
    unsigned char* ws = (unsigned char*)d_ws;

    unsigned short* comp  = (unsigned short*)(ws);             // 4*4096*64*2  = 2,097,152 B
    unsigned short* wtb   = (unsigned short*)(ws + 2097152);   // 9*112*64*2   =   129,024 B
    unsigned short* wct   = (unsigned short*)(ws + 2226176);   // 64*256*2     =    32,768 B
    unsigned short* maskp = (unsigned short*)(ws + 2258944);   // 4*4096*100*2 = 3,276,800 B

    hipLaunchKernelGGL(k_prep,       dim3(316),      dim3(256),  0, stream,
                       w_enc, w_comp, wtb, wct);
    hipLaunchKernelGGL(k_compress,   dim3(64, 4),    dim3(1024), 0, stream,
                       x, wct, b_comp, comp);
    hipLaunchKernelGGL(k_enc,        dim3(128, 4),   dim3(256),  0, stream,
                       comp, wtb, b_enc, maskp);
    hipLaunchKernelGGL(k_reassemble, dim3(4096),     dim3(256),  0, stream,
                       x, maskp, out);
}

// Round 3
// 125.273 us; speedup vs baseline: 1.0264x; 1.0264x over previous
//
#include <hip/hip_runtime.h>

#define HW      4096      // 64*64
#define W_DIM   64
#define C_IN    256
#define NK      25        // 5x5 taps
#define NQ      112       // kq padded 100 -> 112

typedef __bf16 bf16x4 __attribute__((ext_vector_type(4)));
typedef __bf16 bf16x8 __attribute__((ext_vector_type(8)));
typedef float  f32x4  __attribute__((ext_vector_type(4)));
typedef float  f32x2  __attribute__((ext_vector_type(2)));

static __device__ __forceinline__ unsigned short f2bf(float f) {
    unsigned x = __float_as_uint(f);
    return (unsigned short)((x + 0x7fffu + ((x >> 16) & 1u)) >> 16);   // RNE
}
static __device__ __forceinline__ float bflo2f(unsigned u) { return __uint_as_float(u << 16); }
static __device__ __forceinline__ float bfhi2f(unsigned u) { return __uint_as_float(u & 0xffff0000u); }

// ---------------------------------------------------------------------------
// Kernel 0: weight prep.
//  wtb[tap][kq=112 zero-pad][c=64] bf16   (encoder B panels)
//  wct[cc=64][c=256] bf16                 (compress B)
__global__ __launch_bounds__(256) void k_prep(const float* __restrict__ wenc,
                                              const float* __restrict__ wcomp,
                                              unsigned short* __restrict__ wtb,
                                              unsigned short* __restrict__ wct) {
    int idx = blockIdx.x * 256 + threadIdx.x;   // 64512 + 16384 = 80896
    if (idx < 64512) {
        int c = idx & 63;
        int t2 = idx >> 6;
        int kq = t2 % NQ;
        int tap = t2 / NQ;
        float v = (kq < 100) ? wenc[(kq * 64 + c) * 9 + tap] : 0.0f;
        wtb[idx] = f2bf(v);
    } else if (idx < 80896) {
        int j = idx - 64512;
        wct[j] = f2bf(wcomp[j]);
    }
}

// ---------------------------------------------------------------------------
// Kernel 1: MFMA 1x1 compress. GEMM M=64 px (contig p), N=64 cc, K=256 c.
// v3: round-1 tile geometry + LDS layout EXACTLY; 512 threads (8 waves/CU,
// was 4). Wave wv -> (mt = wv>>1, nt pair = 2*(wv&1)): acc[2] = two
// independent 8-deep MFMA chains per wave. Per-block traffic unchanged.
__global__ __launch_bounds__(512) void k_compress(const float* __restrict__ x,
        const unsigned short* __restrict__ wct, const float* __restrict__ bcomp,
        unsigned short* __restrict__ comp) {
    __shared__ unsigned short As[64 * 260];     // 33,280 B
    __shared__ unsigned short Bs[64 * 260];     // 33,280 B
    __shared__ float sbc[64];
    int n = blockIdx.y, p0 = blockIdx.x * 64;
    int tid = threadIdx.x, wv = tid >> 6, lane = tid & 63;   // wv 0..7
    int l15 = lane & 15, l4 = lane >> 4;
    if (tid < 64) sbc[tid] = bcomp[tid];

    const float* xp = x + (size_t)n * C_IN * HW + p0;
#pragma unroll
    for (int s = 0; s < 16; ++s) {              // A: 128 c-pairs x 64 px
        int cp = s * 8 + wv;                    // wave-uniform c-pair
        float a = xp[(size_t)(2 * cp) * HW + lane];
        float b = xp[(size_t)(2 * cp + 1) * HW + lane];
        unsigned pk = (unsigned)f2bf(a) | ((unsigned)f2bf(b) << 16);
        *(unsigned*)(As + lane * 260 + cp * 2) = pk;
    }
    const unsigned* wsrc = (const unsigned*)wct;
#pragma unroll
    for (int s = 0; s < 16; ++s) {              // B: 64 cc x 128 u32
        int slot = s * 512 + tid;
        int cc = slot >> 7, c2 = slot & 127;
        *(unsigned*)(Bs + cc * 260 + c2 * 2) = wsrc[cc * 128 + c2];
    }
    __syncthreads();

    int mt = wv >> 1, nb = (wv & 1) * 2;        // wave-tile: 16 px x 32 cc
    f32x4 acc[2];
#pragma unroll
    for (int j = 0; j < 2; ++j) acc[j] = (f32x4){0.f, 0.f, 0.f, 0.f};
#pragma unroll
    for (int ck = 0; ck < 8; ++ck) {
        int ko = ck * 32 + l4 * 8;              // u16 offset in row
        bf16x4 alo = *(const bf16x4*)(As + (mt * 16 + l15) * 260 + ko);
        bf16x4 ahi = *(const bf16x4*)(As + (mt * 16 + l15) * 260 + ko + 4);
        bf16x8 af = __builtin_shufflevector(alo, ahi, 0, 1, 2, 3, 4, 5, 6, 7);
#pragma unroll
        for (int j = 0; j < 2; ++j) {
            int nt = nb + j;
            bf16x4 blo = *(const bf16x4*)(Bs + (nt * 16 + l15) * 260 + ko);
            bf16x4 bhi = *(const bf16x4*)(Bs + (nt * 16 + l15) * 260 + ko + 4);
            bf16x8 bfr = __builtin_shufflevector(blo, bhi, 0, 1, 2, 3, 4, 5, 6, 7);
            acc[j] = __builtin_amdgcn_mfma_f32_16x16x32_bf16(af, bfr, acc[j], 0, 0, 0);
        }
    }
    unsigned short* op = comp + ((size_t)n * HW + p0 + mt * 16 + l4 * 4) * 64;
#pragma unroll
    for (int reg = 0; reg < 4; ++reg)
#pragma unroll
        for (int j = 0; j < 2; ++j) {
            int cc = (nb + j) * 16 + l15;
            op[(size_t)reg * 64 + cc] = f2bf(acc[j][reg] + sbc[cc]);
        }
}

// ---------------------------------------------------------------------------
// Kernel 2: MFMA 3x3 encoder (64->100) + fused softmax.
// v3: round-1 tile geometry (8x8 px, 100-px halo, grid (64,4)) + LDS layout
// EXACTLY; 512 threads (8 waves/CU, was 4). Wave wv -> (mq = wv&3,
// nt group g = wv>>2: {0..3} or {4..6}). Per-block traffic unchanged.
// Epilogue cross-wave -> 2 extra barriers. Mask stored bf16.
#define CREC    136
#define SB0     13600                // 100 px * 136
#define BSTRIDE 15232                // 112 * 136
#define EPI_PAD 116
__global__ __launch_bounds__(512) void k_enc(
        const unsigned short* __restrict__ comp,
        const unsigned short* __restrict__ wtb,
        const float* __restrict__ benc,
        unsigned short* __restrict__ mask) {
    __shared__ __align__(16) unsigned char smem[SB0 + 2 * BSTRIDE];   // 44,064 B
    __shared__ float sbias[NQ];
    int n = blockIdx.y, tile = blockIdx.x;
    int h0 = (tile >> 3) * 8, w0 = (tile & 7) * 8;
    int tid = threadIdx.x, wv = tid >> 6, lane = tid & 63;   // wv 0..7
    int l15 = lane & 15, l4 = lane >> 4;
    if (tid < NQ) sbias[tid] = (tid < 100) ? benc[tid] : 0.0f;

    // stage comp halo: 100 px x 128 B, zero OOB (conv zero-pad)
    const uint4* csrc = (const uint4*)(comp + (size_t)n * HW * 64);
#pragma unroll
    for (int pass = 0; pass < 2; ++pass) {
        int s = pass * 512 + tid;               // 800 slots
        if (s < 800) {
            int px = s >> 3, j = s & 7;
            int gh = h0 + px / 10 - 1, gw = w0 + px % 10 - 1;
            uint4 v = make_uint4(0u, 0u, 0u, 0u);
            if ((unsigned)gh < 64u && (unsigned)gw < 64u)
                v = csrc[(size_t)(gh * 64 + gw) * 8 + j];
            *(uint2*)(smem + px * CREC + j * 16)     = make_uint2(v.x, v.y);
            *(uint2*)(smem + px * CREC + j * 16 + 8) = make_uint2(v.z, v.w);
        }
    }
    // stage B(0) -> buf0; preload B(1) -> regs
    {
        const uint4* bs = (const uint4*)wtb;
#pragma unroll
        for (int pass = 0; pass < 2; ++pass) {
            int s = pass * 512 + tid;           // 896 slots
            if (s < 896) {
                uint4 v = bs[s];
                int kq = s >> 3, j = s & 7;
                *(uint2*)(smem + SB0 + kq * CREC + j * 16)     = make_uint2(v.x, v.y);
                *(uint2*)(smem + SB0 + kq * CREC + j * 16 + 8) = make_uint2(v.z, v.w);
            }
        }
    }
    uint4 pre[2];
    {
        const uint4* bs = (const uint4*)(wtb + (size_t)1 * NQ * 64);
#pragma unroll
        for (int pass = 0; pass < 2; ++pass) {
            int s = pass * 512 + tid;
            if (s < 896) pre[pass] = bs[s];
        }
    }

    f32x4 acc[4];
#pragma unroll
    for (int k = 0; k < 4; ++k) acc[k] = (f32x4){0.f, 0.f, 0.f, 0.f};
    int mq = wv & 3, g = wv >> 2;               // g=0: nt 0..3, g=1: nt 4..6
    int r_t = 2 * mq + (l15 >> 3), cl = l15 & 7;

    for (int tap = 0; tap < 9; ++tap) {
        __syncthreads();                        // separates buf reads(t-1) from writes(t+1)
        if (tap < 8) {
            unsigned char* nbuf = smem + SB0 + ((tap + 1) & 1) * BSTRIDE;
#pragma unroll
            for (int pass = 0; pass < 2; ++pass) {
                int s = pass * 512 + tid;
                if (s < 896) {
                    int kq = s >> 3, j = s & 7;
                    *(uint2*)(nbuf + kq * CREC + j * 16)     = make_uint2(pre[pass].x, pre[pass].y);
                    *(uint2*)(nbuf + kq * CREC + j * 16 + 8) = make_uint2(pre[pass].z, pre[pass].w);
                }
            }
            if (tap < 7) {
                const uint4* bs = (const uint4*)(wtb + (size_t)(tap + 2) * NQ * 64);
#pragma unroll
                for (int pass = 0; pass < 2; ++pass) {
                    int s = pass * 512 + tid;
                    if (s < 896) pre[pass] = bs[s];
                }
            }
        }
        int ti = tap / 3, tj = tap % 3;
        int apx = (r_t + ti) * 10 + cl + tj;
        const unsigned char* cbuf = smem + SB0 + (tap & 1) * BSTRIDE;
#pragma unroll
        for (int ck = 0; ck < 2; ++ck) {
            int ko = ck * 64 + l4 * 16;         // byte offset in record
            bf16x4 alo = *(const bf16x4*)(smem + apx * CREC + ko);
            bf16x4 ahi = *(const bf16x4*)(smem + apx * CREC + ko + 8);
            bf16x8 af = __builtin_shufflevector(alo, ahi, 0, 1, 2, 3, 4, 5, 6, 7);
#pragma unroll
            for (int k = 0; k < 4; ++k) {
                int nt = g * 4 + k;
                if (nt < 7) {                   // wave-uniform scalar guard
                    bf16x4 blo = *(const bf16x4*)(cbuf + (nt * 16 + l15) * CREC + ko);
                    bf16x4 bhi = *(const bf16x4*)(cbuf + (nt * 16 + l15) * CREC + ko + 8);
                    bf16x8 bfr = __builtin_shufflevector(blo, bhi, 0, 1, 2, 3, 4, 5, 6, 7);
                    acc[k] = __builtin_amdgcn_mfma_f32_16x16x32_bf16(af, bfr, acc[k], 0, 0, 0);
                }
            }
        }
    }
    __syncthreads();                            // B buffers dead; epilogue overlays

    // smE: 64 rows x EPI_PAD f32 = 29,696 B, overlaid on B region (30,464 B)
    float* smE = (float*)(smem + SB0);
    unsigned short* maskn = mask + (size_t)n * HW * 100;
#pragma unroll
    for (int k = 0; k < 4; ++k) {
        int nt = g * 4 + k;
        if (nt < 7) {
            f32x4 v = acc[k];
#pragma unroll
            for (int reg = 0; reg < 4; ++reg)
                smE[(mq * 16 + l4 * 4 + reg) * EPI_PAD + nt * 16 + l15] = v[reg];
        }
    }
    __syncthreads();                            // rows built by 2 waves
    if (tid < 256) {
        int r = tid >> 2, q = tid & 3;          // 64 rows x 4 threads
        float* row = smE + r * EPI_PAD;
        float v[NK], mx = -1e30f;
#pragma unroll
        for (int k = 0; k < NK; ++k) {
            v[k] = row[4 * k + q] + sbias[4 * k + q];
            mx = fmaxf(mx, v[k]);
        }
        float ssum = 0.f;
#pragma unroll
        for (int k = 0; k < NK; ++k) { v[k] = __expf(v[k] - mx); ssum += v[k]; }
        float inv = 1.0f / ssum;
#pragma unroll
        for (int k = 0; k < NK; ++k) row[4 * k + q] = v[k] * inv;
    }
    __syncthreads();                            // store reads cross-wave rows
#pragma unroll
    for (int i = 0; i < 4; ++i) {
        int idx = i * 512 + tid;                // 1600 slots: 64 rows x 25 quads
        if (idx < 1600) {
            int r = idx / 25, f4 = idx % 25;
            int rr = 2 * (r >> 4) + ((r >> 3) & 1), cc2 = r & 7;
            size_t p = (size_t)(h0 + rr) * 64 + (w0 + cc2);
            const float* sp = smE + r * EPI_PAD + f4 * 4;
            unsigned u0 = (unsigned)f2bf(sp[0]) | ((unsigned)f2bf(sp[1]) << 16);
            unsigned u1 = (unsigned)f2bf(sp[2]) | ((unsigned)f2bf(sp[3]) << 16);
            *(uint2*)(maskn + p * 100 + f4 * 4) = make_uint2(u0, u1);
        }
    }
}

// ---------------------------------------------------------------------------
// Kernel 4: reassembly v4 (round-1 verified, unchanged). 8x8 px tile x 16 c,
// flat grid 4096 blocks. LDS 25.3 KB -> 6 blocks/CU (24 waves, 75% occ).
// XCD-aware swizzle -> x halo + mask per-XCD-L2-resident. Mask bf16.
#define XSTR2 20
#define MSTR2 108
__global__ __launch_bounds__(256, 6) void k_reassemble(const float* __restrict__ x,
        const unsigned short* __restrict__ mask, float* __restrict__ out) {
    __shared__ __align__(16) float xs[144 * XSTR2];         // 11,520 B
    __shared__ __align__(16) unsigned short ms[64 * MSTR2]; // 13,824 B
    int flat = blockIdx.x;
    int nf = (flat & 7) * 512 + (flat >> 3);    // XCD-contiguous work ids
    int tile = nf & 63, cg = (nf >> 6) & 15, n = nf >> 10;
    int h0 = (tile >> 3) * 8, w0 = (tile & 7) * 8;
    int tid = threadIdx.x;

    // stage x halo: 12x12 px x 16 c, float2 (gw base even -> pairs never
    // straddle the zero-pad boundary), zero OOB
    const float* xb = x + ((size_t)n * C_IN + cg * 16) * HW;
#pragma unroll
    for (int i = 0; i < 5; ++i) {
        int s = i * 256 + tid;                  // 16c * 12r * 6 pairs = 1152
        if (s < 1152) {
            int c = s / 72, rem = s % 72;
            int r = rem / 6, j = rem % 6;
            int gh = h0 - 2 + r, gw = w0 - 2 + j * 2;
            float2 v = make_float2(0.f, 0.f);
            if ((unsigned)gh < 64u && (unsigned)gw < 64u)
                v = *(const float2*)(xb + (size_t)c * HW + gh * W_DIM + gw);
            int px = r * 12 + j * 2;
            xs[px * XSTR2 + c]       = v.x;
            xs[(px + 1) * XSTR2 + c] = v.y;
        }
    }
    // stage mask: 64 px x 100 bf16, pure uint2 copy (conversion in k_enc)
    const unsigned short* mp = mask + (size_t)n * HW * 100;
#pragma unroll
    for (int i = 0; i < 7; ++i) {
        int s = i * 256 + tid;                  // 64 px * 25 quads = 1600
        if (s < 1600) {
            int px = s / 25, q = s % 25;
            int gp = (h0 + (px >> 3)) * W_DIM + w0 + (px & 7);
            *(uint2*)(ms + px * MSTR2 + q * 4) =
                *(const uint2*)(mp + (size_t)gp * 100 + q * 4);
        }
    }
    __syncthreads();

    int px = tid & 63, w = tid >> 6;            // lane = out px, wave = 4-ch slice
    int wx = px & 7, hy = px >> 3;
    f32x4 acc0 = {0.f, 0.f, 0.f, 0.f}, acc1 = {0.f, 0.f, 0.f, 0.f};
    f32x4 acc2 = {0.f, 0.f, 0.f, 0.f}, acc3 = {0.f, 0.f, 0.f, 0.f};
    const unsigned short* mrow = ms + px * MSTR2;
#pragma unroll
    for (int di = 0; di < 5; ++di)
#pragma unroll
        for (int dj = 0; dj < 5; ++dj) {
            int t = di * 5 + dj;
            uint2 mw = *(const uint2*)(mrow + t * 4);
            f32x4 xv = *(const f32x4*)(xs + ((hy + di) * 12 + wx + dj) * XSTR2 + w * 4);
            acc0 += xv * bflo2f(mw.x);
            acc1 += xv * bfhi2f(mw.x);
            acc2 += xv * bflo2f(mw.y);
            acc3 += xv * bfhi2f(mw.y);
        }
#pragma unroll
    for (int u = 0; u < 4; ++u) {
        float* ob = out + (((size_t)n * C_IN + cg * 16 + w * 4 + u) * 128 + 2 * (h0 + hy)) * 128
                        + 2 * (w0 + wx);
        *(float2*)(ob)       = make_float2(acc0[u], acc1[u]);
        *(float2*)(ob + 128) = make_float2(acc2[u], acc3[u]);
    }
}

// ---------------------------------------------------------------------------
extern "C" void kernel_launch(void* const* d_in, const int* in_sizes, int n_in,
                              void* d_out, int out_size, void* d_ws, size_t ws_size,
                              hipStream_t stream) {
    const float* x      = (const float*)d_in[0];
    const float* w_comp = (const float*)d_in[1];
    const float* b_comp = (const float*)d_in[2];
    const float* w_enc  = (const float*)d_in[3];
    const float* b_enc  = (const float*)d_in[4];
    float* out = (float*)d_out;
    unsigned char* ws = (unsigned char*)d_ws;

    unsigned short* comp  = (unsigned short*)(ws);             // 4*4096*64*2  = 2,097,152 B
    unsigned short* wtb   = (unsigned short*)(ws + 2097152);   // 9*112*64*2   =   129,024 B
    unsigned short* wct   = (unsigned short*)(ws + 2226176);   // 64*256*2     =    32,768 B
    unsigned short* maskp = (unsigned short*)(ws + 2258944);   // 4*4096*100*2 = 3,276,800 B

    hipLaunchKernelGGL(k_prep,       dim3(316),      dim3(256), 0, stream,
                       w_enc, w_comp, wtb, wct);
    hipLaunchKernelGGL(k_compress,   dim3(64, 4),    dim3(512), 0, stream,
                       x, wct, b_comp, comp);
    hipLaunchKernelGGL(k_enc,        dim3(64, 4),    dim3(512), 0, stream,
                       comp, wtb, b_enc, maskp);
    hipLaunchKernelGGL(k_reassemble, dim3(4096),     dim3(256), 0, stream,
                       x, maskp, out);
}